// Round 13
// baseline (674.785 us; speedup 1.0000x reference)
//
#include <hip/hip_runtime.h>
#include <cstdio>
#include <cstdint>

#define CDIV(a,b) (((a)+(b)-1)/(b))

static const int N   = 50000;   // nodes
static const int NE0 = 150000;  // edges w/o self loops
static const int NE  = 200000;  // edges with self loops
static const int H   = 10;      // heads
static const int F   = 78;      // per-head features
static const int C   = 780;     // H*F
static const int G   = 128;     // graphs
static const int KP_GAT = 96;   // per-head K: 78 padded to 3*32
static const int XAGG_LD = 960; // xagg row: 10 heads x 96
static const int CP1 = 800;     // gat_out cols: 10 heads x 80
static const int CP1A = 832;    // allocated ld (13*64) so GCN GEMM runs BK=64
static const int CP2 = 784;     // h2/gcn_out cols: 780 padded to 98*8
static const int POOL_SPLIT = 8;
static const int BM_SPLIT = 8;  // k_build_M cc-loop split
static const int KCAT = 5920;   // merged tail GEMM K: 1504 (fcg2) + 3872 (fc2xt) + 544 (fc1xt)

typedef __attribute__((ext_vector_type(8))) short bf16x8;
typedef __attribute__((ext_vector_type(4))) float f32x4;
typedef __attribute__((ext_vector_type(8))) unsigned short us8;

__device__ __forceinline__ float bf2f(unsigned short u) {
    return __uint_as_float(((unsigned int)u) << 16);
}
__device__ __forceinline__ unsigned short f2bf(float f) {
    unsigned int u = __float_as_uint(f);
    u = (u + 0x7fff + ((u >> 16) & 1)) >> 16;   // RNE
    return (unsigned short)u;
}

// async global->LDS, 16B per lane; LDS dest is wave-uniform base + lane*16
__device__ __forceinline__ void async16(const unsigned short* g, unsigned short* l) {
    __builtin_amdgcn_global_load_lds(
        (const __attribute__((address_space(1))) unsigned int*)g,
        (__attribute__((address_space(3))) unsigned int*)l, 16, 0, 0);
}

// ---------------------------------------------------------------------------
// 256x128-tile BK=64 single-buffer MFMA GEMM (GCN layer). 8 waves (4x2),
// proven R9: ~99us, MfmaUtil ~32%. XOR-swizzled LDS, XCD-chunk swizzle.
// ---------------------------------------------------------------------------
__global__ __launch_bounds__(512)
void gemm_mfma_256(const unsigned short* __restrict__ A,
                   const unsigned short* __restrict__ Bt,
                   unsigned short* __restrict__ Cb,
                   const float* __restrict__ bias, int relu,
                   int M, int Nn, int kSteps, int lda, int ldb, int ldc, int nct)
{
    __shared__ unsigned short As[256][64];   // 32 KB
    __shared__ unsigned short Bs[128][64];   // 16 KB
    const int tid  = threadIdx.x;
    const int lane = tid & 63;
    const int wave = tid >> 6;               // 0..7
    const int wm = (wave >> 1) * 64;         // 0,64,128,192
    const int wn = (wave & 1) * 64;          // 0,64

    const int nwg = gridDim.x;
    const int q8 = nwg >> 3, r8 = nwg & 7;
    const int xcd = blockIdx.x & 7, sub = blockIdx.x >> 3;
    const int wg = (xcd < r8) ? xcd * (q8 + 1) + sub
                              : r8 * (q8 + 1) + (xcd - r8) * q8 + sub;
    const int bm = (wg / nct) * 256, bn = (wg % nct) * 128;

    f32x4 acc[4][4] = {};

    const int mrow = lane & 15, quad = lane >> 4;
    const int srow = lane >> 3;                          // 0..7 within 8-row group
    const int segoff = ((lane & 7) ^ (lane >> 3)) * 8;   // src col for involution

    const unsigned short* gA[4];
    unsigned short* lA[4];
#pragma unroll
    for (int c = 0; c < 4; c++) {
        int r = c * 64 + wave * 8 + srow;
        gA[c] = A + (size_t)min(bm + r, M - 1) * lda + segoff;
        lA[c] = &As[c * 64 + wave * 8][0];
    }
    const unsigned short* gB[2];
    unsigned short* lB[2];
#pragma unroll
    for (int c = 0; c < 2; c++) {
        int r = c * 64 + wave * 8 + srow;
        gB[c] = Bt + (size_t)min(bn + r, Nn - 1) * ldb + segoff;
        lB[c] = &Bs[c * 64 + wave * 8][0];
    }

    for (int ks = 0; ks < kSteps; ks++) {
        const int k0 = ks * 64;
#pragma unroll
        for (int c = 0; c < 4; c++) async16(gA[c] + k0, lA[c]);
#pragma unroll
        for (int c = 0; c < 2; c++) async16(gB[c] + k0, lB[c]);
        __syncthreads();
#pragma unroll
        for (int kk = 0; kk < 2; kk++) {
            bf16x8 af[4], bfr[4];
#pragma unroll
            for (int i = 0; i < 4; i++) {
                int ra = wm + i * 16 + mrow;
                af[i]  = *(const bf16x8*)&As[ra][(((kk * 4 + quad) ^ (ra & 7))) * 8];
                int rb = wn + i * 16 + mrow;
                bfr[i] = *(const bf16x8*)&Bs[rb][(((kk * 4 + quad) ^ (rb & 7))) * 8];
            }
#pragma unroll
            for (int i = 0; i < 4; i++)
#pragma unroll
                for (int j = 0; j < 4; j++)
                    acc[i][j] = __builtin_amdgcn_mfma_f32_16x16x32_bf16(af[i], bfr[j], acc[i][j], 0, 0, 0);
        }
        __syncthreads();
    }

    // epilogue: C/D layout col=lane&15, row=quad*4+reg  [m89-verified]
#pragma unroll
    for (int i = 0; i < 4; i++) {
#pragma unroll
        for (int j = 0; j < 4; j++) {
            int col = bn + wn + j * 16 + mrow;
            if (col >= Nn) continue;
            float bv = bias ? bias[col] : 0.f;
#pragma unroll
            for (int r = 0; r < 4; r++) {
                int row = bm + wm + i * 16 + quad * 4 + r;
                if (row >= M) continue;
                float v = acc[i][j][r] + bv;
                if (relu) v = fmaxf(v, 0.f);
                Cb[(size_t)row * ldc + col] = f2bf(v);
            }
        }
    }
}

// ---------------------------------------------------------------------------
// Head-batched GAT GEMM, 256x128 tile, BK=32, 8 waves (4x2). h==9 blocks
// also zero the gat_out K-pad tail cols [800,832) (fused k_zero_tail).
// ---------------------------------------------------------------------------
__global__ __launch_bounds__(512)
void gemm_gat(const unsigned short* __restrict__ A,   // xagg [N][960]
              const unsigned short* __restrict__ Bt,  // [10][80][96]
              const float* __restrict__ bias,         // [800], h*80+f layout
              unsigned short* __restrict__ Cb)        // gat_out [N][832]
{
    __shared__ unsigned short As[256][32];   // 16 KB
    __shared__ unsigned short Bs[128][32];   // 8 KB
    const int tid  = threadIdx.x;
    const int lane = tid & 63;
    const int wave = tid >> 6;               // 0..7
    const int wm = (wave >> 1) * 64;         // 0,64,128,192
    const int wn = (wave & 1) * 64;          // 0,64
    const int h = blockIdx.y;

    const int nwg = gridDim.x;
    const int q8 = nwg >> 3, r8 = nwg & 7;
    const int xcd = blockIdx.x & 7, sub = blockIdx.x >> 3;
    const int wg = (xcd < r8) ? xcd * (q8 + 1) + sub
                              : r8 * (q8 + 1) + (xcd - r8) * q8 + sub;
    const int bm = wg * 256;

    f32x4 acc[4][4] = {};

    const int mrow = lane & 15, quad = lane >> 4;
    const int subr = lane >> 2;                                 // 0..15
    const int segp = ((lane & 3) ^ ((lane >> 3) & 3)) * 8;      // write-side seg
    const int segr = (quad ^ ((mrow >> 1) & 3)) * 8;            // read-side seg

    const unsigned short* gA0 = A + (size_t)min(bm + wave * 16 + subr,       N - 1) * XAGG_LD + h * KP_GAT + segp;
    const unsigned short* gA1 = A + (size_t)min(bm + 128 + wave * 16 + subr, N - 1) * XAGG_LD + h * KP_GAT + segp;
    const unsigned short* gB0 = Bt + (size_t)(h * 80 + min(wave * 16 + subr, 79)) * KP_GAT + segp;
    unsigned short* lA0 = &As[wave * 16][0];
    unsigned short* lA1 = &As[128 + wave * 16][0];
    unsigned short* lB0 = &Bs[wave * 16][0];

#pragma unroll
    for (int ks = 0; ks < 3; ks++) {
        const int k0 = ks * 32;
        async16(gA0 + k0, lA0);
        async16(gA1 + k0, lA1);
        async16(gB0 + k0, lB0);
        __syncthreads();
        bf16x8 af[4], bfr[4];
#pragma unroll
        for (int i = 0; i < 4; i++) {
            af[i]  = *(const bf16x8*)&As[wm + i * 16 + mrow][segr];
            bfr[i] = *(const bf16x8*)&Bs[wn + i * 16 + mrow][segr];
        }
#pragma unroll
        for (int i = 0; i < 4; i++)
#pragma unroll
            for (int j = 0; j < 4; j++)
                acc[i][j] = __builtin_amdgcn_mfma_f32_16x16x32_bf16(af[i], bfr[j], acc[i][j], 0, 0, 0);
        __syncthreads();
    }

#pragma unroll
    for (int i = 0; i < 4; i++) {
#pragma unroll
        for (int j = 0; j < 4; j++) {
            int cl = wn + j * 16 + mrow;          // local col
            if (cl >= 80) continue;
            float bv = bias[h * 80 + cl];
#pragma unroll
            for (int r = 0; r < 4; r++) {
                int row = bm + wm + i * 16 + quad * 4 + r;
                if (row >= N) continue;
                float v = fmaxf(acc[i][j][r] + bv, 0.f);
                Cb[(size_t)row * CP1A + h * 80 + cl] = f2bf(v);
            }
        }
    }

    // fused tail-zero: h==9 blocks clear K-pad cols [800,832) for their rows
    if (h == 9) {
        for (int idx = tid; idx < 256 * 32; idx += 512) {
            int row = bm + (idx >> 5);
            if (row < N) Cb[(size_t)row * CP1A + CP1 + (idx & 31)] = 0;
        }
    }
}

// ---------------------------------------------------------------------------
// Split-K GEMM (plain single-buffer BK=32) for skinny (M=128) tail GEMMs.
// KS chosen so every split is active (s*per < kSteps).
// ---------------------------------------------------------------------------
__global__ __launch_bounds__(256)
void gemm_mfma_sk(const unsigned short* __restrict__ A,
                  const unsigned short* __restrict__ Bt,
                  float* __restrict__ Cp,
                  int M, int Nn, int kSteps, int lda, int ldb, int nct)
{
    __shared__ unsigned short As[128][32];
    __shared__ unsigned short Bs[128][32];
    const int tid  = threadIdx.x;
    const int lane = tid & 63;
    const int wave = tid >> 6;
    const int wm = (wave >> 1) * 64, wn = (wave & 1) * 64;
    const int bm = (blockIdx.x / nct) * 128, bn = (blockIdx.x % nct) * 128;

    const int split = blockIdx.y, KS = gridDim.y;
    const int per = CDIV(kSteps, KS);
    const int kb = split * per;
    const int ke = min(kb + per, kSteps);

    f32x4 acc[4][4] = {};

    const int mrow = lane & 15, quad = lane >> 4;
    const int subr = lane >> 2;
    const int segp = ((lane & 3) ^ ((lane >> 3) & 3)) * 8;
    const int segr = (quad ^ ((mrow >> 1) & 3)) * 8;

    const unsigned short* gA0 = A  + (size_t)min(bm + wave * 16 + subr,      M - 1)  * lda + segp;
    const unsigned short* gA1 = A  + (size_t)min(bm + 64 + wave * 16 + subr, M - 1)  * lda + segp;
    const unsigned short* gB0 = Bt + (size_t)min(bn + wave * 16 + subr,      Nn - 1) * ldb + segp;
    const unsigned short* gB1 = Bt + (size_t)min(bn + 64 + wave * 16 + subr, Nn - 1) * ldb + segp;
    unsigned short* lA0 = &As[wave * 16][0];
    unsigned short* lA1 = &As[64 + wave * 16][0];
    unsigned short* lB0 = &Bs[wave * 16][0];
    unsigned short* lB1 = &Bs[64 + wave * 16][0];

    for (int ks = kb; ks < ke; ks++) {
        const int k0 = ks * 32;
        async16(gA0 + k0, lA0);
        async16(gA1 + k0, lA1);
        async16(gB0 + k0, lB0);
        async16(gB1 + k0, lB1);
        __syncthreads();
        bf16x8 af[4], bfr[4];
#pragma unroll
        for (int i = 0; i < 4; i++) {
            af[i]  = *(const bf16x8*)&As[wm + i * 16 + mrow][segr];
            bfr[i] = *(const bf16x8*)&Bs[wn + i * 16 + mrow][segr];
        }
#pragma unroll
        for (int i = 0; i < 4; i++)
#pragma unroll
            for (int j = 0; j < 4; j++)
                acc[i][j] = __builtin_amdgcn_mfma_f32_16x16x32_bf16(af[i], bfr[j], acc[i][j], 0, 0, 0);
        __syncthreads();
    }

    float* Cs = Cp + (size_t)split * M * Nn;
#pragma unroll
    for (int i = 0; i < 4; i++) {
#pragma unroll
        for (int j = 0; j < 4; j++) {
            int col = bn + wn + j * 16 + mrow;
            if (col >= Nn) continue;
#pragma unroll
            for (int r = 0; r < 4; r++) {
                int row = bm + wm + i * 16 + quad * 4 + r;
                if (row >= M) continue;
                Cs[(size_t)row * Nn + col] = acc[i][j][r];
            }
        }
    }
}

__global__ void k_sk_reduce(const float* __restrict__ Cp, int KS, int M, int Nn,
                            const float* __restrict__ bias, int relu,
                            unsigned short* __restrict__ Cb, int ldc)
{
    int idx = blockIdx.x * blockDim.x + threadIdx.x;
    if (idx >= M * Nn) return;
    int row = idx / Nn, col = idx % Nn;
    float v = bias ? bias[col] : 0.f;
    for (int s = 0; s < KS; s++) v += Cp[((size_t)s * M + row) * Nn + col];
    if (relu) v = fmaxf(v, 0.f);
    Cb[(size_t)row * ldc + col] = f2bf(v);
}

// final [G,512]bf16 @ [512,1] + b -> d_out; one block (64 lanes) per graph
__global__ void k_fc_out(const unsigned short* __restrict__ f2, const float* __restrict__ W,
                         const float* __restrict__ b, float* __restrict__ out)
{
    int g = blockIdx.x, lane = threadIdx.x;
    float acc = 0.f;
    for (int k = lane; k < 512; k += 64) acc += bf2f(f2[g * 512 + k]) * W[k];
#pragma unroll
    for (int off = 32; off > 0; off >>= 1) acc += __shfl_down(acc, off, 64);
    if (lane == 0) out[g] = acc + b[0];
}

// ---------------------------------------------------------------------------
// casts / weight builds
// ---------------------------------------------------------------------------
__global__ void k_cast_pad_x(const float* __restrict__ x, unsigned short* __restrict__ xb)
{
    int idx = blockIdx.x * blockDim.x + threadIdx.x;
    if (idx >= N * KP_GAT) return;
    int n = idx / KP_GAT, k = idx % KP_GAT;
    float v = (k < F) ? x[(size_t)n * F + k] : 0.f;
    xb[idx] = f2bf(v);
}

// LDS-tiled transpose-cast: W[K][Nn] fp32 -> Wt[Nn rows, ld stride] bf16,
// cols k<Kpad written (zero-padded beyond K). ld decouples row stride from
// Kpad so transposes can write directly into Wcat segments.
__global__ void k_transpose_cast_t(const float* __restrict__ W, unsigned short* __restrict__ Wt,
                                   int K, int Nn, int Kpad, int ld)
{
    __shared__ float tile[32][33];
    int k0 = blockIdx.x * 32, n0 = blockIdx.y * 32;
    int tx = threadIdx.x, ty = threadIdx.y;
    for (int r = ty; r < 32; r += 8) {
        int k = k0 + r, n = n0 + tx;
        tile[r][tx] = (k < K && n < Nn) ? W[(size_t)k * Nn + n] : 0.f;
    }
    __syncthreads();
    for (int r = ty; r < 32; r += 8) {
        int n = n0 + r, k = k0 + tx;
        if (n < Nn && k < Kpad) Wt[(size_t)n * ld + k] = f2bf(tile[tx][r]);
    }
}

// Wgat_t[(h*80+f)][k] == [10][80][96]: col h*78+f of W_gat; zero pads.
__global__ void k_build_Wgat_t(const float* __restrict__ W_gat, unsigned short* __restrict__ Wt)
{
    int idx = blockIdx.x * blockDim.x + threadIdx.x;
    if (idx >= KP_GAT * CP1) return;
    int k = idx / CP1, n = idx % CP1;
    int h = n / 80, f = n % 80;
    float v = (k < F && f < F) ? W_gat[(size_t)k * C + h * F + f] : 0.f;
    Wt[(size_t)n * KP_GAT + k] = f2bf(v);
}

// merged bias builds: block 0 -> bgat_p[800], block 1 -> bcat[384]
__global__ void k_build_biases(const float* __restrict__ b_gat, float* __restrict__ bgat_p,
                               const float* __restrict__ b_fcg2, const float* __restrict__ b_fc1xt,
                               const float* __restrict__ b_fc2xt, float* __restrict__ bcat)
{
    int i = threadIdx.x + blockIdx.x * 0;   // per-block role
    if (blockIdx.x == 0) {
        for (int j = i; j < CP1; j += blockDim.x) {
            int h = j / 80, f = j % 80;
            bgat_p[j] = (f < F) ? b_gat[h * F + f] : 0.f;
        }
    } else {
        for (int j = i; j < 384; j += blockDim.x)
            bcat[j] = (j < 128) ? b_fcg2[j] : ((j < 256) ? b_fc1xt[j - 128] : b_fc2xt[j - 256]);
    }
}

// Wgcn_t[n][kpad=CP1A], kpad col h*80+f maps W_gcn row h*78+f; pads pre-zeroed.
__global__ void k_build_Wgcn_t(const float* __restrict__ W_gcn, unsigned short* __restrict__ Wt)
{
    int idx = blockIdx.x * blockDim.x + threadIdx.x;
    if (idx >= C * CP2) return;
    int ko = idx / CP2, n = idx % CP2;
    int h = ko / F, f = ko % F;
    float v = (n < C) ? W_gcn[(size_t)ko * C + n] : 0.f;
    Wt[(size_t)n * CP1A + h * 80 + f] = f2bf(v);
}

// ---------------------------------------------------------------------------
// attention logits
// ---------------------------------------------------------------------------
__global__ void k_Vsd(const float* __restrict__ W_gat, const float* __restrict__ att_src,
                      const float* __restrict__ att_dst, float* __restrict__ V_s,
                      float* __restrict__ V_d)
{
    int idx = blockIdx.x * blockDim.x + threadIdx.x;
    if (idx >= F * H) return;
    int k = idx / H, h = idx % H;
    const float* wr = W_gat + (size_t)k * C + h * F;
    const float* as = att_src + h * F;
    const float* ad = att_dst + h * F;
    float s = 0.f, d = 0.f;
    for (int f = 0; f < F; f++) { float w = wr[f]; s += w * as[f]; d += w * ad[f]; }
    V_s[idx] = s; V_d[idx] = d;
}

__global__ void k_ascores(const float* __restrict__ x, const float* __restrict__ V_s,
                          const float* __restrict__ V_d, float* __restrict__ a_s,
                          float* __restrict__ a_d)
{
    __shared__ float Vs[F * H], Vd[F * H];
    int t = threadIdx.x;
    for (int i = t; i < F * H; i += 256) { Vs[i] = V_s[i]; Vd[i] = V_d[i]; }
    __syncthreads();
    int n = blockIdx.x * 256 + t;
    if (n >= N) return;
    const float* xr = x + (size_t)n * F;
    float accs[H] = {}, accd[H] = {};
    for (int k = 0; k < F; k++) {
        float xv = xr[k];
        const float* vs = &Vs[k * H];
        const float* vd = &Vd[k * H];
#pragma unroll
        for (int h = 0; h < H; h++) { accs[h] += xv * vs[h]; accd[h] += xv * vd[h]; }
    }
    for (int h = 0; h < H; h++) { a_s[n * H + h] = accs[h]; a_d[n * H + h] = accd[h]; }
}

// ---------------------------------------------------------------------------
// CSR build (self-loops appended). fill_csr_ev also writes the leaky-relu
// attention logits at the CSR position; no dsts array.
// ---------------------------------------------------------------------------
__global__ void count_deg(const int* __restrict__ ei, int* __restrict__ deg)
{
    int e = blockIdx.x * blockDim.x + threadIdx.x;
    if (e >= NE) return;
    int d = (e < NE0) ? ei[NE0 + e] : (e - NE0);
    atomicAdd(&deg[d], 1);
}

// prefix sum over deg -> row_start; also emits dinv (fused old k_dinv)
__global__ void scan_int(const int* __restrict__ cnt, int* __restrict__ row_start, int n,
                         float* __restrict__ dinv)
{
    __shared__ int partial[1024];
    int tid = threadIdx.x;
    int per = CDIV(n, 1024);
    int start = tid * per, end = min(start + per, n);
    int sum = 0;
    for (int i = start; i < end; i++) sum += cnt[i];
    partial[tid] = sum;
    __syncthreads();
    for (int off = 1; off < 1024; off *= 2) {
        int v = (tid >= off) ? partial[tid - off] : 0;
        __syncthreads();
        partial[tid] += v;
        __syncthreads();
    }
    int base = (tid > 0) ? partial[tid - 1] : 0;
    for (int i = start; i < end; i++) {
        row_start[i] = base;
        int d = cnt[i];
        base += d;
        dinv[i] = (d > 0) ? 1.f / sqrtf((float)d) : 0.f;
    }
    if (tid == 1023) row_start[n] = base;
}

__global__ void fill_csr_ev(const int* __restrict__ ei, const int* __restrict__ row_start,
                            int* __restrict__ fill_cnt, int* __restrict__ srcs,
                            const float* __restrict__ a_s, const float* __restrict__ a_d,
                            float* __restrict__ evb)
{
    int e = blockIdx.x * blockDim.x + threadIdx.x;
    if (e >= NE) return;
    int sr = (e < NE0) ? ei[e] : (e - NE0);
    int d  = (e < NE0) ? ei[NE0 + e] : (e - NE0);
    int pos = row_start[d] + atomicAdd(&fill_cnt[d], 1);
    srcs[pos] = sr;
    const float* as = a_s + sr * H;
    const float* ad = a_d + d * H;
    float* ev = evb + (size_t)pos * H;
#pragma unroll
    for (int h = 0; h < H; h++) {
        float v = as[h] + ad[h];
        ev[h] = (v > 0.f) ? v : 0.2f * v;
    }
}

// batch is SORTED: gstart[g] = lower_bound(batch, g)
__global__ void k_gstart(const int* __restrict__ batch, int* __restrict__ gstart)
{
    int g = blockIdx.x * blockDim.x + threadIdx.x;
    if (g > G) return;
    int lo = 0, hi = N;
    while (lo < hi) {
        int mid = (lo + hi) >> 1;
        if (batch[mid] < g) lo = mid + 1; else hi = mid;
    }
    gstart[g] = lo;
}

// per (node, head): online max/sum over CSR run, rewrite evb in place as alpha
__global__ void k_softmax_alpha(const int* __restrict__ row_start, float* __restrict__ evb)
{
    int idx = blockIdx.x * blockDim.x + threadIdx.x;
    if (idx >= N * H) return;
    int n = idx / H, h = idx % H;
    int rs = row_start[n], re = row_start[n + 1];
    float m = -INFINITY, s = 0.f;
    for (int i = rs; i < re; i++) {
        float ev = evb[(size_t)i * H + h];
        if (ev <= m) {
            s += expf(ev - m);
        } else {
            s = s * expf(m - ev) + 1.f;
            m = ev;
        }
    }
    float inv = 1.f / (s + 1e-16f);
    for (int i = rs; i < re; i++) {
        float ev = evb[(size_t)i * H + h];
        evb[(size_t)i * H + h] = expf(ev - m) * inv;
    }
}

// ---------------------------------------------------------------------------
// GAT aggregation on x (linearity swap), edge-unrolled x2.
// ---------------------------------------------------------------------------
__global__ __launch_bounds__(128)
void gat_agg_x(const unsigned short* __restrict__ xb, const float* __restrict__ alpha,
               const int* __restrict__ srcs, const int* __restrict__ row_start,
               unsigned short* __restrict__ xagg)
{
    int n = blockIdx.x;
    int f = threadIdx.x;
    if (f >= KP_GAT) return;
    int rs = row_start[n], re = row_start[n + 1];
    float acc[H] = {};
    int i = rs;
    for (; i + 1 < re; i += 2) {
        int sr0 = srcs[i], sr1 = srcs[i + 1];
        float xv0 = bf2f(xb[(size_t)sr0 * KP_GAT + f]);
        float xv1 = bf2f(xb[(size_t)sr1 * KP_GAT + f]);
        const float* al0 = alpha + (size_t)i * H;
        const float* al1 = alpha + (size_t)(i + 1) * H;
#pragma unroll
        for (int h = 0; h < H; h++) acc[h] += al0[h] * xv0 + al1[h] * xv1;
    }
    if (i < re) {
        int sr = srcs[i];
        float xv = bf2f(xb[(size_t)sr * KP_GAT + f]);
        const float* al = alpha + (size_t)i * H;
#pragma unroll
        for (int h = 0; h < H; h++) acc[h] += al[h] * xv;
    }
#pragma unroll
    for (int h = 0; h < H; h++)
        xagg[(size_t)n * XAGG_LD + h * KP_GAT + f] = f2bf(acc[h]);
}

// GCN aggregation: h2 bf16 [N][784] -> gcn_out bf16 [N][784]; edge-unrolled x2
__global__ __launch_bounds__(128)
void gcn_agg(const unsigned short* __restrict__ h2, const float* __restrict__ dinv,
             const int* __restrict__ srcs, const int* __restrict__ row_start,
             const float* __restrict__ b_gcn, unsigned short* __restrict__ out)
{
    int n = blockIdx.x;
    int c = threadIdx.x * 8;
    if (c >= CP2) return;
    float dn = dinv[n];
    int rs = row_start[n], re = row_start[n + 1];
    float acc[8] = {};
    int i = rs;
    for (; i + 1 < re; i += 2) {
        int sr0 = srcs[i], sr1 = srcs[i + 1];
        float d0 = dinv[sr0], d1 = dinv[sr1];
        us8 v0 = *(const us8*)&h2[(size_t)sr0 * CP2 + c];
        us8 v1 = *(const us8*)&h2[(size_t)sr1 * CP2 + c];
#pragma unroll
        for (int j = 0; j < 8; j++) acc[j] += d0 * bf2f(v0[j]) + d1 * bf2f(v1[j]);
    }
    if (i < re) {
        int sr = srcs[i];
        float d = dinv[sr];
        us8 v = *(const us8*)&h2[(size_t)sr * CP2 + c];
#pragma unroll
        for (int j = 0; j < 8; j++) acc[j] += d * bf2f(v[j]);
    }
    us8 o;
#pragma unroll
    for (int j = 0; j < 8; j++) {
        int col = c + j;
        float r = (col < C) ? fmaxf(acc[j] * dn + b_gcn[col], 0.f) : 0.f;
        o[j] = f2bf(r);
    }
    *(us8*)&out[(size_t)n * CP2 + c] = o;
}

// ---------------------------------------------------------------------------
// max+mean pool, node-split (atomics; values >= 0 so uint-max == float-max)
// ---------------------------------------------------------------------------
__global__ __launch_bounds__(128)
void k_pool(const unsigned short* __restrict__ hh, const int* __restrict__ gstart,
            float* __restrict__ gfeat)
{
    int g = blockIdx.x;
    int c = threadIdx.x * 8;
    if (c >= CP2) return;
    int s0 = gstart[g], e0 = gstart[g + 1];
    int len = e0 - s0;
    if (len <= 0) return;
    int per = CDIV(len, (int)gridDim.y);
    int s = s0 + (int)blockIdx.y * per;
    int e = min(s + per, e0);
    if (s >= e) return;
    float mx[8] = {}, sm[8] = {};
    for (int n = s; n < e; n++) {
        us8 v = *(const us8*)&hh[(size_t)n * CP2 + c];
#pragma unroll
        for (int j = 0; j < 8; j++) { float f = bf2f(v[j]); mx[j] = fmaxf(mx[j], f); sm[j] += f; }
    }
#pragma unroll
    for (int j = 0; j < 8; j++) {
        int col = c + j;
        if (col < C) {
            atomicMax((unsigned int*)&gfeat[g * 1560 + col], __float_as_uint(mx[j]));
            atomicAdd(&gfeat[g * 1560 + 780 + col], sm[j]);
        }
    }
}

// fused pool-finalize + bf16 cast: gfeat fp32 [G][1560] -> gfeat_b [G][1568]
__global__ void k_pool_cast(const float* __restrict__ gfeat, const int* __restrict__ gstart,
                            unsigned short* __restrict__ dst)
{
    int idx = blockIdx.x * blockDim.x + threadIdx.x;
    if (idx >= G * 1568) return;
    int g = idx / 1568, k = idx % 1568;
    float v = 0.f;
    if (k < 780) {
        v = gfeat[g * 1560 + k];
    } else if (k < 1560) {
        float cnt = fmaxf((float)(gstart[g + 1] - gstart[g]), 1.f);
        v = gfeat[g * 1560 + k] * (1.f / cnt);
    }
    dst[idx] = f2bf(v);
}

// ---------------------------------------------------------------------------
// protein branches (k_build_M split BM_SPLIT ways + reduce)
// ---------------------------------------------------------------------------
__global__ void k_build_M(const int* __restrict__ t2, const float* __restrict__ Wc2,
                          float* __restrict__ Mbuf)
{
    __shared__ float Ml[26 * 256];
    int b = blockIdx.x, t = threadIdx.x, s = blockIdx.y;
    for (int j = t; j < 26 * 256; j += 256) Ml[j] = 0.f;
    __syncthreads();
    int o = t >> 3, k = t & 7;
    const int* tb = t2 + b * 1000;
    int c0 = s * (1000 / BM_SPLIT), c1 = c0 + (1000 / BM_SPLIT);
    for (int cc = c0; cc < c1; cc++) {
        int tok = tb[cc];
        Ml[tok * 256 + t] += Wc2[o * 8000 + cc * 8 + k];
    }
    __syncthreads();
    float* Mb = Mbuf + ((size_t)b * BM_SPLIT + s) * (26 * 256);
    for (int j = t; j < 26 * 256; j += 256) Mb[j] = Ml[j];
}

__global__ void k_reduce_M(const float* __restrict__ Mbuf, float* __restrict__ Mfin)
{
    int idx = blockIdx.x * blockDim.x + threadIdx.x;
    if (idx >= G * 26 * 256) return;
    int b = idx / (26 * 256), j = idx % (26 * 256);
    const float* p = Mbuf + (size_t)b * BM_SPLIT * (26 * 256);
    float v = 0.f;
#pragma unroll
    for (int s = 0; s < BM_SPLIT; s++) v += p[(size_t)s * (26 * 256) + j];
    Mfin[idx] = v;
}

__global__ void k_conv2(const float* __restrict__ Mbuf, const float* __restrict__ emb,
                        const float* __restrict__ bc2, unsigned short* __restrict__ dst, int ld)
{
    int idx = blockIdx.x * blockDim.x + threadIdx.x;
    if (idx >= G * 3872) return;
    int b = idx / 3872, r = idx % 3872;
    int o = r / 121, l = r % 121;
    const float* Mb = Mbuf + (size_t)b * (26 * 256);
    float acc = bc2[o];
    for (int t = 0; t < 26; t++) {
        const float* mrow = Mb + t * 256 + o * 8;
        const float* erow = emb + t * 128 + l;
#pragma unroll
        for (int k = 0; k < 8; k++) acc += mrow[k] * erow[k];
    }
    dst[(size_t)b * ld + r] = f2bf(acc);
}

__global__ void k_conv1(const float* __restrict__ t1, const float* __restrict__ Wc1,
                        const float* __restrict__ bc1, unsigned short* __restrict__ dst, int ld)
{
    int idx = blockIdx.x * blockDim.x + threadIdx.x;
    if (idx >= G * 544) return;
    int b = idx / 544, r = idx % 544;
    int o = r / 17, l = r % 17;
    float acc = bc1[o];
    const float* xb = t1 + b * 480;
    const float* wo = Wc1 + o * 160;
    for (int cc = 0; cc < 20; cc++) {
        const float* xr = xb + cc * 24 + l;
        const float* wr = wo + cc * 8;
#pragma unroll
        for (int k = 0; k < 8; k++) acc += xr[k] * wr[k];
    }
    dst[(size_t)b * ld + r] = f2bf(acc);
}

// ---------------------------------------------------------------------------
extern "C" void kernel_launch(void* const* d_in, const int* in_sizes, int n_in,
                              void* d_out, int out_size, void* d_ws, size_t ws_size,
                              hipStream_t stream)
{
    const float* x       = (const float*)d_in[0];
    const int*   ei      = (const int*)  d_in[1];
    const int*   batch   = (const int*)  d_in[2];
    const float* t1      = (const float*)d_in[3];
    const int*   t2      = (const int*)  d_in[4];
    const float* W_gat   = (const float*)d_in[5];
    const float* att_src = (const float*)d_in[6];
    const float* att_dst = (const float*)d_in[7];
    const float* b_gat   = (const float*)d_in[8];
    const float* W_gcn   = (const float*)d_in[9];
    const float* b_gcn   = (const float*)d_in[10];
    const float* W_fcg1  = (const float*)d_in[11];
    const float* b_fcg1  = (const float*)d_in[12];
    const float* W_fcg2  = (const float*)d_in[13];
    const float* b_fcg2  = (const float*)d_in[14];
    const float* emb     = (const float*)d_in[15];
    const float* Wc2     = (const float*)d_in[16];
    const float* bc2     = (const float*)d_in[17];
    const float* W_fc2xt = (const float*)d_in[18];
    const float* b_fc2xt = (const float*)d_in[19];
    const float* Wc1     = (const float*)d_in[20];
    const float* bc1     = (const float*)d_in[21];
    const float* W_fc1xt = (const float*)d_in[22];
    const float* b_fc1xt = (const float*)d_in[23];
    const float* W_fc1   = (const float*)d_in[24];
    const float* b_fc1   = (const float*)d_in[25];
    const float* W_fc2   = (const float*)d_in[26];
    const float* b_fc2   = (const float*)d_in[27];
    const float* W_out   = (const float*)d_in[28];
    const float* b_out   = (const float*)d_in[29];

    char* wsb = (char*)d_ws;
    size_t off = 0;
    auto alloc = [&](size_t bytes) -> char* {
        char* p = wsb + off;
        off += (bytes + 255) & ~(size_t)255;
        return p;
    };

    unsigned short* h_buf   = (unsigned short*)alloc((size_t)N * XAGG_LD * 2); // xagg [N][960]; then h2 [N][784]
    unsigned short* gat_out = (unsigned short*)alloc((size_t)N * CP1A * 2);    // [N][832]; reused as gcn_out [N][784]
    unsigned short* xb      = (unsigned short*)alloc((size_t)N * KP_GAT * 2);
    unsigned short* Wgat_t  = (unsigned short*)alloc((size_t)CP1 * KP_GAT * 2);
    unsigned short* Wgcn_t  = (unsigned short*)alloc((size_t)CP2 * CP1A * 2);
    unsigned short* Wfcg1_t  = (unsigned short*)alloc((size_t)1500 * 1568 * 2);
    unsigned short* Wfc1_t   = (unsigned short*)alloc((size_t)1024 * 384 * 2);
    unsigned short* Wfc2_t   = (unsigned short*)alloc((size_t)512 * 1024 * 2);
    unsigned short* Wcat     = (unsigned short*)alloc((size_t)384 * KCAT * 2);  // block-diag, transposes write in place
    unsigned short* Acat     = (unsigned short*)alloc((size_t)G * KCAT * 2);    // [128][5920]
    unsigned short* gfeat_b  = (unsigned short*)alloc((size_t)G * 1568 * 2);
    unsigned short* xc_b     = (unsigned short*)alloc((size_t)G * 384 * 2);
    unsigned short* f1_b     = (unsigned short*)alloc((size_t)G * 1024 * 2);
    unsigned short* f2_b     = (unsigned short*)alloc((size_t)G * 512 * 2);
    float* skbuf  = (float*)alloc((size_t)7 * G * 1500 * 4);   // max split-K user: fcg1 KS=7 (covers 24*384, 6*1024, 16*512)
    float* bgat_p = (float*)alloc((size_t)CP1 * 4);
    float* bcat   = (float*)alloc((size_t)384 * 4);
    float* V_s    = (float*)alloc((size_t)F * H * 4);
    float* V_d    = (float*)alloc((size_t)F * H * 4);
    float* a_s    = (float*)alloc((size_t)N * H * 4);
    float* a_d    = (float*)alloc((size_t)N * H * 4);
    float* evb    = (float*)alloc((size_t)NE * H * 4);
    float* dinv   = (float*)alloc((size_t)N * 4);
    float* gfeat  = (float*)alloc((size_t)G * 1560 * 4);
    float* Mbuf   = (float*)alloc((size_t)G * BM_SPLIT * 26 * 256 * 4);
    float* Mfin   = (float*)alloc((size_t)G * 26 * 256 * 4);
    int* deg       = (int*)alloc((size_t)N * 4);
    int* row_start = (int*)alloc((size_t)(N + 1) * 4);
    int* fill_cnt  = (int*)alloc((size_t)N * 4);
    int* srcs      = (int*)alloc((size_t)NE * 4);
    int* gstart    = (int*)alloc((size_t)(G + 1) * 4);

    if (off > ws_size) {
        fprintf(stderr, "kernel_launch: workspace too small: need %zu have %zu\n", off, ws_size);
        return;
    }

    hipMemsetAsync(deg, 0, (size_t)N * 4, stream);
    hipMemsetAsync(fill_cnt, 0, (size_t)N * 4, stream);
    hipMemsetAsync(Acat, 0, (size_t)G * KCAT * 2, stream);     // gaps/K-pads must be 0 (NaN x 0 = NaN!)
    hipMemsetAsync(Wcat, 0, (size_t)384 * KCAT * 2, stream);   // off-diagonal blocks must be 0
    hipMemsetAsync(Wgcn_t, 0, (size_t)CP2 * CP1A * 2, stream); // pad k cols must be 0
    hipMemsetAsync(gfeat, 0, (size_t)G * 1560 * 4, stream);    // pool atomics accumulate

    dim3 tb(32, 8);

    // ---- weight builds + input cast ----
    k_cast_pad_x<<<CDIV(N * KP_GAT, 256), 256, 0, stream>>>(x, xb);
    k_build_Wgat_t<<<CDIV(KP_GAT * CP1, 256), 256, 0, stream>>>(W_gat, Wgat_t);
    k_build_biases<<<2, 256, 0, stream>>>(b_gat, bgat_p, b_fcg2, b_fc1xt, b_fc2xt, bcat);
    k_build_Wgcn_t<<<CDIV(C * CP2, 256), 256, 0, stream>>>(W_gcn, Wgcn_t);
    k_transpose_cast_t<<<dim3(CDIV(1568,32), CDIV(1500,32)), tb, 0, stream>>>(W_fcg1, Wfcg1_t, 1560, 1500, 1568, 1568);
    // fcg2 / fc2xt / fc1xt transposed DIRECTLY into Wcat segments (ld=KCAT):
    k_transpose_cast_t<<<dim3(CDIV(1504,32), CDIV(128,32)),  tb, 0, stream>>>(W_fcg2, Wcat, 1500, 128, 1504, KCAT);
    k_transpose_cast_t<<<dim3(CDIV(3872,32), CDIV(128,32)),  tb, 0, stream>>>(W_fc2xt, Wcat + (size_t)256 * KCAT + 1504, 3872, 128, 3872, KCAT);
    k_transpose_cast_t<<<dim3(CDIV(544,32),  CDIV(128,32)),  tb, 0, stream>>>(W_fc1xt, Wcat + (size_t)128 * KCAT + 5376, 544, 128, 544, KCAT);
    k_transpose_cast_t<<<dim3(CDIV(384,32),  CDIV(1024,32)), tb, 0, stream>>>(W_fc1, Wfc1_t, 384, 1024, 384, 384);
    k_transpose_cast_t<<<dim3(CDIV(1024,32), CDIV(512,32)),  tb, 0, stream>>>(W_fc2, Wfc2_t, 1024, 512, 1024, 1024);

    // ---- attention logits ----
    k_Vsd<<<CDIV(F * H, 256), 256, 0, stream>>>(W_gat, att_src, att_dst, V_s, V_d);
    k_ascores<<<CDIV(N, 256), 256, 0, stream>>>(x, V_s, V_d, a_s, a_d);

    // ---- CSR + graph ranges ----
    count_deg<<<CDIV(NE, 256), 256, 0, stream>>>(ei, deg);
    scan_int<<<1, 1024, 0, stream>>>(deg, row_start, N, dinv);   // + fused dinv
    fill_csr_ev<<<CDIV(NE, 256), 256, 0, stream>>>(ei, row_start, fill_cnt, srcs, a_s, a_d, evb);
    k_gstart<<<1, 256, 0, stream>>>(batch, gstart);   // batch sorted: binary search

    // ---- softmax (fused stats+alpha in place) ----
    k_softmax_alpha<<<CDIV(N * H, 256), 256, 0, stream>>>(row_start, evb);

    // ---- protein branches (independent; fill Acat segments early) ----
    k_build_M<<<dim3(G, BM_SPLIT), 256, 0, stream>>>(t2, Wc2, Mbuf);
    k_reduce_M<<<CDIV(G * 26 * 256, 256), 256, 0, stream>>>(Mbuf, Mfin);
    k_conv2<<<CDIV(G * 3872, 256), 256, 0, stream>>>(Mfin, emb, bc2, Acat + 1504, KCAT);
    k_conv1<<<CDIV(G * 544, 256), 256, 0, stream>>>(t1, Wc1, bc1, Acat + 5376, KCAT);

    // ---- GAT (linearity-swapped): aggregate x, then per-head GEMM ----
    gat_agg_x<<<N, 128, 0, stream>>>(xb, evb, srcs, row_start, h_buf);
    gemm_gat<<<dim3(CDIV(N, 256), H), 512, 0, stream>>>(h_buf, Wgat_t, bgat_p, gat_out);

    // ---- GCN: h2 = gat_out @ W_gcn  (256x128 tile, BK=64, K=832) ----
    {
        int rt = CDIV(N, 256), nct = CDIV(CP2, 128);
        gemm_mfma_256<<<rt * nct, 512, 0, stream>>>(gat_out, Wgcn_t, h_buf, nullptr, 0,
                                                    N, CP2, CP1A / 64, CP1A, CP1A, CP2, nct);
    }
    unsigned short* gcn_out = gat_out;
    gcn_agg<<<N, 128, 0, stream>>>(h_buf, dinv, srcs, row_start, b_gcn, gcn_out);
    k_pool<<<dim3(G, POOL_SPLIT), 128, 0, stream>>>(gcn_out, gstart, gfeat);
    k_pool_cast<<<CDIV(G * 1568, 256), 256, 0, stream>>>(gfeat, gstart, gfeat_b);

    // ---- graph FC: fcg1 -> Acat cols [0,1500); KS=7 (49 steps -> 7/split) ----
    gemm_mfma_sk<<<dim3(CDIV(1500,128), 7), 256, 0, stream>>>(gfeat_b, Wfcg1_t, skbuf,
                                                              G, 1500, 1568/32, 1568, 1568, CDIV(1500,128));
    k_sk_reduce<<<CDIV(G*1500, 256), 256, 0, stream>>>(skbuf, 7, G, 1500, b_fcg1, 1, Acat, KCAT);

    // ---- merged tail GEMM: xc = Acat @ Wcat^T; KS=24 (185 steps -> 8/split) ----
    gemm_mfma_sk<<<dim3(3, 24), 256, 0, stream>>>(Acat, Wcat, skbuf,
                                                  G, 384, KCAT/32, KCAT, KCAT, 3);
    k_sk_reduce<<<CDIV(G*384, 256), 256, 0, stream>>>(skbuf, 24, G, 384, bcat, 0, xc_b, 384);

    // ---- head: fc1 KS=6 (12 steps -> 2/split), fc2 KS=16 (32 -> 2/split) ----
    gemm_mfma_sk<<<dim3(CDIV(1024,128), 6), 256, 0, stream>>>(xc_b, Wfc1_t, skbuf,
                                                              G, 1024, 384/32, 384, 384, CDIV(1024,128));
    k_sk_reduce<<<CDIV(G*1024, 256), 256, 0, stream>>>(skbuf, 6, G, 1024, b_fc1, 1, f1_b, 1024);
    gemm_mfma_sk<<<dim3(CDIV(512,128), 16), 256, 0, stream>>>(f1_b, Wfc2_t, skbuf,
                                                              G, 512, 1024/32, 1024, 1024, CDIV(512,128));
    k_sk_reduce<<<CDIV(G*512, 256), 256, 0, stream>>>(skbuf, 16, G, 512, b_fc2, 1, f2_b, 512);
    k_fc_out<<<G, 64, 0, stream>>>(f2_b, W_out, b_out, (float*)d_out);
}

// Round 14
// 579.548 us; speedup vs baseline: 1.1643x; 1.1643x over previous
//
#include <hip/hip_runtime.h>
#include <cstdio>
#include <cstdint>

#define CDIV(a,b) (((a)+(b)-1)/(b))

static const int N   = 50000;   // nodes
static const int NE0 = 150000;  // edges w/o self loops
static const int NE  = 200000;  // edges with self loops
static const int H   = 10;      // heads
static const int F   = 78;      // per-head features
static const int C   = 780;     // H*F
static const int G   = 128;     // graphs
static const int KP_GAT = 96;   // per-head K: 78 padded to 3*32
static const int XAGG_LD = 960; // xagg row: 10 heads x 96
static const int CP1 = 800;     // gat_out cols: 10 heads x 80
static const int CP1A = 832;    // allocated ld (13*64) so GCN GEMM runs BK=64
static const int CP2 = 784;     // h2/gcn_out cols: 780 padded to 98*8
static const int POOL_SPLIT = 8;
static const int BM_SPLIT = 8;  // k_build_M cc-loop split
static const int KCAT = 5920;   // merged tail GEMM K: 1504 (fcg2) + 3872 (fc2xt) + 544 (fc1xt)
static const int SCAN_B = 256;
static const int SCAN_NB = CDIV(N, SCAN_B);   // 196

typedef __attribute__((ext_vector_type(8))) short bf16x8;
typedef __attribute__((ext_vector_type(4))) float f32x4;
typedef __attribute__((ext_vector_type(8))) unsigned short us8;

__device__ __forceinline__ float bf2f(unsigned short u) {
    return __uint_as_float(((unsigned int)u) << 16);
}
__device__ __forceinline__ unsigned short f2bf(float f) {
    unsigned int u = __float_as_uint(f);
    u = (u + 0x7fff + ((u >> 16) & 1)) >> 16;   // RNE
    return (unsigned short)u;
}

// async global->LDS, 16B per lane; LDS dest is wave-uniform base + lane*16
__device__ __forceinline__ void async16(const unsigned short* g, unsigned short* l) {
    __builtin_amdgcn_global_load_lds(
        (const __attribute__((address_space(1))) unsigned int*)g,
        (__attribute__((address_space(3))) unsigned int*)l, 16, 0, 0);
}

// ---------------------------------------------------------------------------
// 256x128-tile BK=64 single-buffer MFMA GEMM (GCN layer). 8 waves (4x2),
// proven R9: ~99us, MfmaUtil ~32%. XOR-swizzled LDS, XCD-chunk swizzle.
// ---------------------------------------------------------------------------
__global__ __launch_bounds__(512)
void gemm_mfma_256(const unsigned short* __restrict__ A,
                   const unsigned short* __restrict__ Bt,
                   unsigned short* __restrict__ Cb,
                   const float* __restrict__ bias, int relu,
                   int M, int Nn, int kSteps, int lda, int ldb, int ldc, int nct)
{
    __shared__ unsigned short As[256][64];   // 32 KB
    __shared__ unsigned short Bs[128][64];   // 16 KB
    const int tid  = threadIdx.x;
    const int lane = tid & 63;
    const int wave = tid >> 6;               // 0..7
    const int wm = (wave >> 1) * 64;         // 0,64,128,192
    const int wn = (wave & 1) * 64;          // 0,64

    const int nwg = gridDim.x;
    const int q8 = nwg >> 3, r8 = nwg & 7;
    const int xcd = blockIdx.x & 7, sub = blockIdx.x >> 3;
    const int wg = (xcd < r8) ? xcd * (q8 + 1) + sub
                              : r8 * (q8 + 1) + (xcd - r8) * q8 + sub;
    const int bm = (wg / nct) * 256, bn = (wg % nct) * 128;

    f32x4 acc[4][4] = {};

    const int mrow = lane & 15, quad = lane >> 4;
    const int srow = lane >> 3;                          // 0..7 within 8-row group
    const int segoff = ((lane & 7) ^ (lane >> 3)) * 8;   // src col for involution

    const unsigned short* gA[4];
    unsigned short* lA[4];
#pragma unroll
    for (int c = 0; c < 4; c++) {
        int r = c * 64 + wave * 8 + srow;
        gA[c] = A + (size_t)min(bm + r, M - 1) * lda + segoff;
        lA[c] = &As[c * 64 + wave * 8][0];
    }
    const unsigned short* gB[2];
    unsigned short* lB[2];
#pragma unroll
    for (int c = 0; c < 2; c++) {
        int r = c * 64 + wave * 8 + srow;
        gB[c] = Bt + (size_t)min(bn + r, Nn - 1) * ldb + segoff;
        lB[c] = &Bs[c * 64 + wave * 8][0];
    }

    for (int ks = 0; ks < kSteps; ks++) {
        const int k0 = ks * 64;
#pragma unroll
        for (int c = 0; c < 4; c++) async16(gA[c] + k0, lA[c]);
#pragma unroll
        for (int c = 0; c < 2; c++) async16(gB[c] + k0, lB[c]);
        __syncthreads();
#pragma unroll
        for (int kk = 0; kk < 2; kk++) {
            bf16x8 af[4], bfr[4];
#pragma unroll
            for (int i = 0; i < 4; i++) {
                int ra = wm + i * 16 + mrow;
                af[i]  = *(const bf16x8*)&As[ra][(((kk * 4 + quad) ^ (ra & 7))) * 8];
                int rb = wn + i * 16 + mrow;
                bfr[i] = *(const bf16x8*)&Bs[rb][(((kk * 4 + quad) ^ (rb & 7))) * 8];
            }
#pragma unroll
            for (int i = 0; i < 4; i++)
#pragma unroll
                for (int j = 0; j < 4; j++)
                    acc[i][j] = __builtin_amdgcn_mfma_f32_16x16x32_bf16(af[i], bfr[j], acc[i][j], 0, 0, 0);
        }
        __syncthreads();
    }

    // epilogue: C/D layout col=lane&15, row=quad*4+reg  [m89-verified]
#pragma unroll
    for (int i = 0; i < 4; i++) {
#pragma unroll
        for (int j = 0; j < 4; j++) {
            int col = bn + wn + j * 16 + mrow;
            if (col >= Nn) continue;
            float bv = bias ? bias[col] : 0.f;
#pragma unroll
            for (int r = 0; r < 4; r++) {
                int row = bm + wm + i * 16 + quad * 4 + r;
                if (row >= M) continue;
                float v = acc[i][j][r] + bv;
                if (relu) v = fmaxf(v, 0.f);
                Cb[(size_t)row * ldc + col] = f2bf(v);
            }
        }
    }
}

// ---------------------------------------------------------------------------
// Head-batched GAT GEMM, 256x128 tile, BK=32, 8 waves (4x2). h==9 blocks
// also zero the gat_out K-pad tail cols [800,832) (fused k_zero_tail).
// ---------------------------------------------------------------------------
__global__ __launch_bounds__(512)
void gemm_gat(const unsigned short* __restrict__ A,   // xagg [N][960]
              const unsigned short* __restrict__ Bt,  // [10][80][96]
              const float* __restrict__ bias,         // [800], h*80+f layout
              unsigned short* __restrict__ Cb)        // gat_out [N][832]
{
    __shared__ unsigned short As[256][32];   // 16 KB
    __shared__ unsigned short Bs[128][32];   // 8 KB
    const int tid  = threadIdx.x;
    const int lane = tid & 63;
    const int wave = tid >> 6;               // 0..7
    const int wm = (wave >> 1) * 64;         // 0,64,128,192
    const int wn = (wave & 1) * 64;          // 0,64
    const int h = blockIdx.y;

    const int nwg = gridDim.x;
    const int q8 = nwg >> 3, r8 = nwg & 7;
    const int xcd = blockIdx.x & 7, sub = blockIdx.x >> 3;
    const int wg = (xcd < r8) ? xcd * (q8 + 1) + sub
                              : r8 * (q8 + 1) + (xcd - r8) * q8 + sub;
    const int bm = wg * 256;

    f32x4 acc[4][4] = {};

    const int mrow = lane & 15, quad = lane >> 4;
    const int subr = lane >> 2;                                 // 0..15
    const int segp = ((lane & 3) ^ ((lane >> 3) & 3)) * 8;      // write-side seg
    const int segr = (quad ^ ((mrow >> 1) & 3)) * 8;            // read-side seg

    const unsigned short* gA0 = A + (size_t)min(bm + wave * 16 + subr,       N - 1) * XAGG_LD + h * KP_GAT + segp;
    const unsigned short* gA1 = A + (size_t)min(bm + 128 + wave * 16 + subr, N - 1) * XAGG_LD + h * KP_GAT + segp;
    const unsigned short* gB0 = Bt + (size_t)(h * 80 + min(wave * 16 + subr, 79)) * KP_GAT + segp;
    unsigned short* lA0 = &As[wave * 16][0];
    unsigned short* lA1 = &As[128 + wave * 16][0];
    unsigned short* lB0 = &Bs[wave * 16][0];

#pragma unroll
    for (int ks = 0; ks < 3; ks++) {
        const int k0 = ks * 32;
        async16(gA0 + k0, lA0);
        async16(gA1 + k0, lA1);
        async16(gB0 + k0, lB0);
        __syncthreads();
        bf16x8 af[4], bfr[4];
#pragma unroll
        for (int i = 0; i < 4; i++) {
            af[i]  = *(const bf16x8*)&As[wm + i * 16 + mrow][segr];
            bfr[i] = *(const bf16x8*)&Bs[wn + i * 16 + mrow][segr];
        }
#pragma unroll
        for (int i = 0; i < 4; i++)
#pragma unroll
            for (int j = 0; j < 4; j++)
                acc[i][j] = __builtin_amdgcn_mfma_f32_16x16x32_bf16(af[i], bfr[j], acc[i][j], 0, 0, 0);
        __syncthreads();
    }

#pragma unroll
    for (int i = 0; i < 4; i++) {
#pragma unroll
        for (int j = 0; j < 4; j++) {
            int cl = wn + j * 16 + mrow;          // local col
            if (cl >= 80) continue;
            float bv = bias[h * 80 + cl];
#pragma unroll
            for (int r = 0; r < 4; r++) {
                int row = bm + wm + i * 16 + quad * 4 + r;
                if (row >= N) continue;
                float v = fmaxf(acc[i][j][r] + bv, 0.f);
                Cb[(size_t)row * CP1A + h * 80 + cl] = f2bf(v);
            }
        }
    }

    // fused tail-zero: h==9 blocks clear K-pad cols [800,832) for their rows
    if (h == 9) {
        for (int idx = tid; idx < 256 * 32; idx += 512) {
            int row = bm + (idx >> 5);
            if (row < N) Cb[(size_t)row * CP1A + CP1 + (idx & 31)] = 0;
        }
    }
}

// ---------------------------------------------------------------------------
// Split-K GEMM (plain single-buffer BK=32) for skinny (M=128) tail GEMMs.
// KS chosen so every split is active (s*per < kSteps).
// ---------------------------------------------------------------------------
__global__ __launch_bounds__(256)
void gemm_mfma_sk(const unsigned short* __restrict__ A,
                  const unsigned short* __restrict__ Bt,
                  float* __restrict__ Cp,
                  int M, int Nn, int kSteps, int lda, int ldb, int nct)
{
    __shared__ unsigned short As[128][32];
    __shared__ unsigned short Bs[128][32];
    const int tid  = threadIdx.x;
    const int lane = tid & 63;
    const int wave = tid >> 6;
    const int wm = (wave >> 1) * 64, wn = (wave & 1) * 64;
    const int bm = (blockIdx.x / nct) * 128, bn = (blockIdx.x % nct) * 128;

    const int split = blockIdx.y, KS = gridDim.y;
    const int per = CDIV(kSteps, KS);
    const int kb = split * per;
    const int ke = min(kb + per, kSteps);

    f32x4 acc[4][4] = {};

    const int mrow = lane & 15, quad = lane >> 4;
    const int subr = lane >> 2;
    const int segp = ((lane & 3) ^ ((lane >> 3) & 3)) * 8;
    const int segr = (quad ^ ((mrow >> 1) & 3)) * 8;

    const unsigned short* gA0 = A  + (size_t)min(bm + wave * 16 + subr,      M - 1)  * lda + segp;
    const unsigned short* gA1 = A  + (size_t)min(bm + 64 + wave * 16 + subr, M - 1)  * lda + segp;
    const unsigned short* gB0 = Bt + (size_t)min(bn + wave * 16 + subr,      Nn - 1) * ldb + segp;
    const unsigned short* gB1 = Bt + (size_t)min(bn + 64 + wave * 16 + subr, Nn - 1) * ldb + segp;
    unsigned short* lA0 = &As[wave * 16][0];
    unsigned short* lA1 = &As[64 + wave * 16][0];
    unsigned short* lB0 = &Bs[wave * 16][0];
    unsigned short* lB1 = &Bs[64 + wave * 16][0];

    for (int ks = kb; ks < ke; ks++) {
        const int k0 = ks * 32;
        async16(gA0 + k0, lA0);
        async16(gA1 + k0, lA1);
        async16(gB0 + k0, lB0);
        async16(gB1 + k0, lB1);
        __syncthreads();
        bf16x8 af[4], bfr[4];
#pragma unroll
        for (int i = 0; i < 4; i++) {
            af[i]  = *(const bf16x8*)&As[wm + i * 16 + mrow][segr];
            bfr[i] = *(const bf16x8*)&Bs[wn + i * 16 + mrow][segr];
        }
#pragma unroll
        for (int i = 0; i < 4; i++)
#pragma unroll
            for (int j = 0; j < 4; j++)
                acc[i][j] = __builtin_amdgcn_mfma_f32_16x16x32_bf16(af[i], bfr[j], acc[i][j], 0, 0, 0);
        __syncthreads();
    }

    float* Cs = Cp + (size_t)split * M * Nn;
#pragma unroll
    for (int i = 0; i < 4; i++) {
#pragma unroll
        for (int j = 0; j < 4; j++) {
            int col = bn + wn + j * 16 + mrow;
            if (col >= Nn) continue;
#pragma unroll
            for (int r = 0; r < 4; r++) {
                int row = bm + wm + i * 16 + quad * 4 + r;
                if (row >= M) continue;
                Cs[(size_t)row * Nn + col] = acc[i][j][r];
            }
        }
    }
}

__global__ void k_sk_reduce(const float* __restrict__ Cp, int KS, int M, int Nn,
                            const float* __restrict__ bias, int relu,
                            unsigned short* __restrict__ Cb, int ldc)
{
    int idx = blockIdx.x * blockDim.x + threadIdx.x;
    if (idx >= M * Nn) return;
    int row = idx / Nn, col = idx % Nn;
    float v = bias ? bias[col] : 0.f;
    for (int s = 0; s < KS; s++) v += Cp[((size_t)s * M + row) * Nn + col];
    if (relu) v = fmaxf(v, 0.f);
    Cb[(size_t)row * ldc + col] = f2bf(v);
}

// final [G,512]bf16 @ [512,1] + b -> d_out; one block (64 lanes) per graph
__global__ void k_fc_out(const unsigned short* __restrict__ f2, const float* __restrict__ W,
                         const float* __restrict__ b, float* __restrict__ out)
{
    int g = blockIdx.x, lane = threadIdx.x;
    float acc = 0.f;
    for (int k = lane; k < 512; k += 64) acc += bf2f(f2[g * 512 + k]) * W[k];
#pragma unroll
    for (int off = 32; off > 0; off >>= 1) acc += __shfl_down(acc, off, 64);
    if (lane == 0) out[g] = acc + b[0];
}

// ---------------------------------------------------------------------------
// casts / weight builds
// ---------------------------------------------------------------------------
__global__ void k_cast_pad_x(const float* __restrict__ x, unsigned short* __restrict__ xb)
{
    int idx = blockIdx.x * blockDim.x + threadIdx.x;
    if (idx >= N * KP_GAT) return;
    int n = idx / KP_GAT, k = idx % KP_GAT;
    float v = (k < F) ? x[(size_t)n * F + k] : 0.f;
    xb[idx] = f2bf(v);
}

// LDS-tiled transpose-cast: W[K][Nn] fp32 -> Wt[Nn rows, ld stride] bf16.
__global__ void k_transpose_cast_t(const float* __restrict__ W, unsigned short* __restrict__ Wt,
                                   int K, int Nn, int Kpad, int ld)
{
    __shared__ float tile[32][33];
    int k0 = blockIdx.x * 32, n0 = blockIdx.y * 32;
    int tx = threadIdx.x, ty = threadIdx.y;
    for (int r = ty; r < 32; r += 8) {
        int k = k0 + r, n = n0 + tx;
        tile[r][tx] = (k < K && n < Nn) ? W[(size_t)k * Nn + n] : 0.f;
    }
    __syncthreads();
    for (int r = ty; r < 32; r += 8) {
        int n = n0 + r, k = k0 + tx;
        if (n < Nn && k < Kpad) Wt[(size_t)n * ld + k] = f2bf(tile[tx][r]);
    }
}

// Wgat_t[(h*80+f)][k] == [10][80][96]: col h*78+f of W_gat; zero pads.
__global__ void k_build_Wgat_t(const float* __restrict__ W_gat, unsigned short* __restrict__ Wt)
{
    int idx = blockIdx.x * blockDim.x + threadIdx.x;
    if (idx >= KP_GAT * CP1) return;
    int k = idx / CP1, n = idx % CP1;
    int h = n / 80, f = n % 80;
    float v = (k < F && f < F) ? W_gat[(size_t)k * C + h * F + f] : 0.f;
    Wt[(size_t)n * KP_GAT + k] = f2bf(v);
}

// merged bias builds: block 0 -> bgat_p[800], block 1 -> bcat[384]
__global__ void k_build_biases(const float* __restrict__ b_gat, float* __restrict__ bgat_p,
                               const float* __restrict__ b_fcg2, const float* __restrict__ b_fc1xt,
                               const float* __restrict__ b_fc2xt, float* __restrict__ bcat)
{
    int i = threadIdx.x;
    if (blockIdx.x == 0) {
        for (int j = i; j < CP1; j += blockDim.x) {
            int h = j / 80, f = j % 80;
            bgat_p[j] = (f < F) ? b_gat[h * F + f] : 0.f;
        }
    } else {
        for (int j = i; j < 384; j += blockDim.x)
            bcat[j] = (j < 128) ? b_fcg2[j] : ((j < 256) ? b_fc1xt[j - 128] : b_fc2xt[j - 256]);
    }
}

// Wgcn_t[n][kpad=CP1A], kpad col h*80+f maps W_gcn row h*78+f; pads pre-zeroed.
__global__ void k_build_Wgcn_t(const float* __restrict__ W_gcn, unsigned short* __restrict__ Wt)
{
    int idx = blockIdx.x * blockDim.x + threadIdx.x;
    if (idx >= C * CP2) return;
    int ko = idx / CP2, n = idx % CP2;
    int h = ko / F, f = ko % F;
    float v = (n < C) ? W_gcn[(size_t)ko * C + n] : 0.f;
    Wt[(size_t)n * CP1A + h * 80 + f] = f2bf(v);
}

// ---------------------------------------------------------------------------
// attention logits
// ---------------------------------------------------------------------------
__global__ void k_Vsd(const float* __restrict__ W_gat, const float* __restrict__ att_src,
                      const float* __restrict__ att_dst, float* __restrict__ V_s,
                      float* __restrict__ V_d)
{
    int idx = blockIdx.x * blockDim.x + threadIdx.x;
    if (idx >= F * H) return;
    int k = idx / H, h = idx % H;
    const float* wr = W_gat + (size_t)k * C + h * F;
    const float* as = att_src + h * F;
    const float* ad = att_dst + h * F;
    float s = 0.f, d = 0.f;
    for (int f = 0; f < F; f++) { float w = wr[f]; s += w * as[f]; d += w * ad[f]; }
    V_s[idx] = s; V_d[idx] = d;
}

__global__ void k_ascores(const float* __restrict__ x, const float* __restrict__ V_s,
                          const float* __restrict__ V_d, float* __restrict__ a_s,
                          float* __restrict__ a_d)
{
    __shared__ float Vs[F * H], Vd[F * H];
    int t = threadIdx.x;
    for (int i = t; i < F * H; i += 256) { Vs[i] = V_s[i]; Vd[i] = V_d[i]; }
    __syncthreads();
    int n = blockIdx.x * 256 + t;
    if (n >= N) return;
    const float* xr = x + (size_t)n * F;
    float accs[H] = {}, accd[H] = {};
    for (int k = 0; k < F; k++) {
        float xv = xr[k];
        const float* vs = &Vs[k * H];
        const float* vd = &Vd[k * H];
#pragma unroll
        for (int h = 0; h < H; h++) { accs[h] += xv * vs[h]; accd[h] += xv * vd[h]; }
    }
    for (int h = 0; h < H; h++) { a_s[n * H + h] = accs[h]; a_d[n * H + h] = accd[h]; }
}

// ---------------------------------------------------------------------------
// CSR build (self-loops appended). fill_csr_ev also writes the leaky-relu
// attention logits at the CSR position; no dsts array.
// ---------------------------------------------------------------------------
__global__ void count_deg(const int* __restrict__ ei, int* __restrict__ deg)
{
    int e = blockIdx.x * blockDim.x + threadIdx.x;
    if (e >= NE) return;
    int d = (e < NE0) ? ei[NE0 + e] : (e - NE0);
    atomicAdd(&deg[d], 1);
}

// ---------------------------------------------------------------------------
// 3-phase parallel prefix scan over deg (replaces the single-block scan_int
// which was ~109 us latency-bound on one CU). Phase 3 also emits dinv.
// ---------------------------------------------------------------------------
__global__ void k_scan_pass1(const int* __restrict__ cnt, int* __restrict__ bsum)
{
    __shared__ int sh[SCAN_B];
    int i = blockIdx.x * SCAN_B + threadIdx.x;
    sh[threadIdx.x] = (i < N) ? cnt[i] : 0;
    __syncthreads();
    for (int off = SCAN_B / 2; off > 0; off >>= 1) {
        if (threadIdx.x < off) sh[threadIdx.x] += sh[threadIdx.x + off];
        __syncthreads();
    }
    if (threadIdx.x == 0) bsum[blockIdx.x] = sh[0];
}

// single block (SCAN_NB=196 <= 256): exclusive scan of block sums; writes
// bofs[b] and row_start[N] = total
__global__ void k_scan_mid(const int* __restrict__ bsum, int* __restrict__ bofs,
                           int* __restrict__ row_start)
{
    __shared__ int sh[SCAN_B];
    int t = threadIdx.x;
    int v0 = (t < SCAN_NB) ? bsum[t] : 0;
    sh[t] = v0;
    __syncthreads();
    for (int off = 1; off < SCAN_B; off <<= 1) {
        int v = (t >= off) ? sh[t - off] : 0;
        __syncthreads();
        sh[t] += v;
        __syncthreads();
    }
    if (t < SCAN_NB) bofs[t] = sh[t] - v0;       // exclusive prefix
    if (t == SCAN_NB - 1) row_start[N] = sh[t];  // total
}

__global__ void k_scan_pass3(const int* __restrict__ cnt, const int* __restrict__ bofs,
                             int* __restrict__ row_start, float* __restrict__ dinv)
{
    __shared__ int sh[SCAN_B];
    int i = blockIdx.x * SCAN_B + threadIdx.x;
    int v0 = (i < N) ? cnt[i] : 0;
    sh[threadIdx.x] = v0;
    __syncthreads();
    for (int off = 1; off < SCAN_B; off <<= 1) {
        int v = (threadIdx.x >= off) ? sh[threadIdx.x - off] : 0;
        __syncthreads();
        sh[threadIdx.x] += v;
        __syncthreads();
    }
    if (i < N) {
        row_start[i] = sh[threadIdx.x] - v0 + bofs[blockIdx.x];   // exclusive
        dinv[i] = (v0 > 0) ? 1.f / sqrtf((float)v0) : 0.f;
    }
}

__global__ void fill_csr_ev(const int* __restrict__ ei, const int* __restrict__ row_start,
                            int* __restrict__ fill_cnt, int* __restrict__ srcs,
                            const float* __restrict__ a_s, const float* __restrict__ a_d,
                            float* __restrict__ evb)
{
    int e = blockIdx.x * blockDim.x + threadIdx.x;
    if (e >= NE) return;
    int sr = (e < NE0) ? ei[e] : (e - NE0);
    int d  = (e < NE0) ? ei[NE0 + e] : (e - NE0);
    int pos = row_start[d] + atomicAdd(&fill_cnt[d], 1);
    srcs[pos] = sr;
    const float* as = a_s + sr * H;
    const float* ad = a_d + d * H;
    float* ev = evb + (size_t)pos * H;
#pragma unroll
    for (int h = 0; h < H; h++) {
        float v = as[h] + ad[h];
        ev[h] = (v > 0.f) ? v : 0.2f * v;
    }
}

// batch is SORTED: gstart[g] = lower_bound(batch, g)
__global__ void k_gstart(const int* __restrict__ batch, int* __restrict__ gstart)
{
    int g = blockIdx.x * blockDim.x + threadIdx.x;
    if (g > G) return;
    int lo = 0, hi = N;
    while (lo < hi) {
        int mid = (lo + hi) >> 1;
        if (batch[mid] < g) lo = mid + 1; else hi = mid;
    }
    gstart[g] = lo;
}

// per (node, head): online max/sum over CSR run, rewrite evb in place as alpha
__global__ void k_softmax_alpha(const int* __restrict__ row_start, float* __restrict__ evb)
{
    int idx = blockIdx.x * blockDim.x + threadIdx.x;
    if (idx >= N * H) return;
    int n = idx / H, h = idx % H;
    int rs = row_start[n], re = row_start[n + 1];
    float m = -INFINITY, s = 0.f;
    for (int i = rs; i < re; i++) {
        float ev = evb[(size_t)i * H + h];
        if (ev <= m) {
            s += expf(ev - m);
        } else {
            s = s * expf(m - ev) + 1.f;
            m = ev;
        }
    }
    float inv = 1.f / (s + 1e-16f);
    for (int i = rs; i < re; i++) {
        float ev = evb[(size_t)i * H + h];
        evb[(size_t)i * H + h] = expf(ev - m) * inv;
    }
}

// ---------------------------------------------------------------------------
// GAT aggregation on x (linearity swap), edge-unrolled x2.
// ---------------------------------------------------------------------------
__global__ __launch_bounds__(128)
void gat_agg_x(const unsigned short* __restrict__ xb, const float* __restrict__ alpha,
               const int* __restrict__ srcs, const int* __restrict__ row_start,
               unsigned short* __restrict__ xagg)
{
    int n = blockIdx.x;
    int f = threadIdx.x;
    if (f >= KP_GAT) return;
    int rs = row_start[n], re = row_start[n + 1];
    float acc[H] = {};
    int i = rs;
    for (; i + 1 < re; i += 2) {
        int sr0 = srcs[i], sr1 = srcs[i + 1];
        float xv0 = bf2f(xb[(size_t)sr0 * KP_GAT + f]);
        float xv1 = bf2f(xb[(size_t)sr1 * KP_GAT + f]);
        const float* al0 = alpha + (size_t)i * H;
        const float* al1 = alpha + (size_t)(i + 1) * H;
#pragma unroll
        for (int h = 0; h < H; h++) acc[h] += al0[h] * xv0 + al1[h] * xv1;
    }
    if (i < re) {
        int sr = srcs[i];
        float xv = bf2f(xb[(size_t)sr * KP_GAT + f]);
        const float* al = alpha + (size_t)i * H;
#pragma unroll
        for (int h = 0; h < H; h++) acc[h] += al[h] * xv;
    }
#pragma unroll
    for (int h = 0; h < H; h++)
        xagg[(size_t)n * XAGG_LD + h * KP_GAT + f] = f2bf(acc[h]);
}

// GCN aggregation: h2 bf16 [N][784] -> gcn_out bf16 [N][784]; edge-unrolled x2
__global__ __launch_bounds__(128)
void gcn_agg(const unsigned short* __restrict__ h2, const float* __restrict__ dinv,
             const int* __restrict__ srcs, const int* __restrict__ row_start,
             const float* __restrict__ b_gcn, unsigned short* __restrict__ out)
{
    int n = blockIdx.x;
    int c = threadIdx.x * 8;
    if (c >= CP2) return;
    float dn = dinv[n];
    int rs = row_start[n], re = row_start[n + 1];
    float acc[8] = {};
    int i = rs;
    for (; i + 1 < re; i += 2) {
        int sr0 = srcs[i], sr1 = srcs[i + 1];
        float d0 = dinv[sr0], d1 = dinv[sr1];
        us8 v0 = *(const us8*)&h2[(size_t)sr0 * CP2 + c];
        us8 v1 = *(const us8*)&h2[(size_t)sr1 * CP2 + c];
#pragma unroll
        for (int j = 0; j < 8; j++) acc[j] += d0 * bf2f(v0[j]) + d1 * bf2f(v1[j]);
    }
    if (i < re) {
        int sr = srcs[i];
        float d = dinv[sr];
        us8 v = *(const us8*)&h2[(size_t)sr * CP2 + c];
#pragma unroll
        for (int j = 0; j < 8; j++) acc[j] += d * bf2f(v[j]);
    }
    us8 o;
#pragma unroll
    for (int j = 0; j < 8; j++) {
        int col = c + j;
        float r = (col < C) ? fmaxf(acc[j] * dn + b_gcn[col], 0.f) : 0.f;
        o[j] = f2bf(r);
    }
    *(us8*)&out[(size_t)n * CP2 + c] = o;
}

// ---------------------------------------------------------------------------
// max+mean pool, node-split (atomics; values >= 0 so uint-max == float-max)
// ---------------------------------------------------------------------------
__global__ __launch_bounds__(128)
void k_pool(const unsigned short* __restrict__ hh, const int* __restrict__ gstart,
            float* __restrict__ gfeat)
{
    int g = blockIdx.x;
    int c = threadIdx.x * 8;
    if (c >= CP2) return;
    int s0 = gstart[g], e0 = gstart[g + 1];
    int len = e0 - s0;
    if (len <= 0) return;
    int per = CDIV(len, (int)gridDim.y);
    int s = s0 + (int)blockIdx.y * per;
    int e = min(s + per, e0);
    if (s >= e) return;
    float mx[8] = {}, sm[8] = {};
    for (int n = s; n < e; n++) {
        us8 v = *(const us8*)&hh[(size_t)n * CP2 + c];
#pragma unroll
        for (int j = 0; j < 8; j++) { float f = bf2f(v[j]); mx[j] = fmaxf(mx[j], f); sm[j] += f; }
    }
#pragma unroll
    for (int j = 0; j < 8; j++) {
        int col = c + j;
        if (col < C) {
            atomicMax((unsigned int*)&gfeat[g * 1560 + col], __float_as_uint(mx[j]));
            atomicAdd(&gfeat[g * 1560 + 780 + col], sm[j]);
        }
    }
}

// fused pool-finalize + bf16 cast: gfeat fp32 [G][1560] -> gfeat_b [G][1568]
__global__ void k_pool_cast(const float* __restrict__ gfeat, const int* __restrict__ gstart,
                            unsigned short* __restrict__ dst)
{
    int idx = blockIdx.x * blockDim.x + threadIdx.x;
    if (idx >= G * 1568) return;
    int g = idx / 1568, k = idx % 1568;
    float v = 0.f;
    if (k < 780) {
        v = gfeat[g * 1560 + k];
    } else if (k < 1560) {
        float cnt = fmaxf((float)(gstart[g + 1] - gstart[g]), 1.f);
        v = gfeat[g * 1560 + k] * (1.f / cnt);
    }
    dst[idx] = f2bf(v);
}

// ---------------------------------------------------------------------------
// protein branches (k_build_M split BM_SPLIT ways + reduce)
// ---------------------------------------------------------------------------
__global__ void k_build_M(const int* __restrict__ t2, const float* __restrict__ Wc2,
                          float* __restrict__ Mbuf)
{
    __shared__ float Ml[26 * 256];
    int b = blockIdx.x, t = threadIdx.x, s = blockIdx.y;
    for (int j = t; j < 26 * 256; j += 256) Ml[j] = 0.f;
    __syncthreads();
    int o = t >> 3, k = t & 7;
    const int* tb = t2 + b * 1000;
    int c0 = s * (1000 / BM_SPLIT), c1 = c0 + (1000 / BM_SPLIT);
    for (int cc = c0; cc < c1; cc++) {
        int tok = tb[cc];
        Ml[tok * 256 + t] += Wc2[o * 8000 + cc * 8 + k];
    }
    __syncthreads();
    float* Mb = Mbuf + ((size_t)b * BM_SPLIT + s) * (26 * 256);
    for (int j = t; j < 26 * 256; j += 256) Mb[j] = Ml[j];
}

__global__ void k_reduce_M(const float* __restrict__ Mbuf, float* __restrict__ Mfin)
{
    int idx = blockIdx.x * blockDim.x + threadIdx.x;
    if (idx >= G * 26 * 256) return;
    int b = idx / (26 * 256), j = idx % (26 * 256);
    const float* p = Mbuf + (size_t)b * BM_SPLIT * (26 * 256);
    float v = 0.f;
#pragma unroll
    for (int s = 0; s < BM_SPLIT; s++) v += p[(size_t)s * (26 * 256) + j];
    Mfin[idx] = v;
}

__global__ void k_conv2(const float* __restrict__ Mbuf, const float* __restrict__ emb,
                        const float* __restrict__ bc2, unsigned short* __restrict__ dst, int ld)
{
    int idx = blockIdx.x * blockDim.x + threadIdx.x;
    if (idx >= G * 3872) return;
    int b = idx / 3872, r = idx % 3872;
    int o = r / 121, l = r % 121;
    const float* Mb = Mbuf + (size_t)b * (26 * 256);
    float acc = bc2[o];
    for (int t = 0; t < 26; t++) {
        const float* mrow = Mb + t * 256 + o * 8;
        const float* erow = emb + t * 128 + l;
#pragma unroll
        for (int k = 0; k < 8; k++) acc += mrow[k] * erow[k];
    }
    dst[(size_t)b * ld + r] = f2bf(acc);
}

__global__ void k_conv1(const float* __restrict__ t1, const float* __restrict__ Wc1,
                        const float* __restrict__ bc1, unsigned short* __restrict__ dst, int ld)
{
    int idx = blockIdx.x * blockDim.x + threadIdx.x;
    if (idx >= G * 544) return;
    int b = idx / 544, r = idx % 544;
    int o = r / 17, l = r % 17;
    float acc = bc1[o];
    const float* xb = t1 + b * 480;
    const float* wo = Wc1 + o * 160;
    for (int cc = 0; cc < 20; cc++) {
        const float* xr = xb + cc * 24 + l;
        const float* wr = wo + cc * 8;
#pragma unroll
        for (int k = 0; k < 8; k++) acc += xr[k] * wr[k];
    }
    dst[(size_t)b * ld + r] = f2bf(acc);
}

// ---------------------------------------------------------------------------
extern "C" void kernel_launch(void* const* d_in, const int* in_sizes, int n_in,
                              void* d_out, int out_size, void* d_ws, size_t ws_size,
                              hipStream_t stream)
{
    const float* x       = (const float*)d_in[0];
    const int*   ei      = (const int*)  d_in[1];
    const int*   batch   = (const int*)  d_in[2];
    const float* t1      = (const float*)d_in[3];
    const int*   t2      = (const int*)  d_in[4];
    const float* W_gat   = (const float*)d_in[5];
    const float* att_src = (const float*)d_in[6];
    const float* att_dst = (const float*)d_in[7];
    const float* b_gat   = (const float*)d_in[8];
    const float* W_gcn   = (const float*)d_in[9];
    const float* b_gcn   = (const float*)d_in[10];
    const float* W_fcg1  = (const float*)d_in[11];
    const float* b_fcg1  = (const float*)d_in[12];
    const float* W_fcg2  = (const float*)d_in[13];
    const float* b_fcg2  = (const float*)d_in[14];
    const float* emb     = (const float*)d_in[15];
    const float* Wc2     = (const float*)d_in[16];
    const float* bc2     = (const float*)d_in[17];
    const float* W_fc2xt = (const float*)d_in[18];
    const float* b_fc2xt = (const float*)d_in[19];
    const float* Wc1     = (const float*)d_in[20];
    const float* bc1     = (const float*)d_in[21];
    const float* W_fc1xt = (const float*)d_in[22];
    const float* b_fc1xt = (const float*)d_in[23];
    const float* W_fc1   = (const float*)d_in[24];
    const float* b_fc1   = (const float*)d_in[25];
    const float* W_fc2   = (const float*)d_in[26];
    const float* b_fc2   = (const float*)d_in[27];
    const float* W_out   = (const float*)d_in[28];
    const float* b_out   = (const float*)d_in[29];

    char* wsb = (char*)d_ws;
    size_t off = 0;
    auto alloc = [&](size_t bytes) -> char* {
        char* p = wsb + off;
        off += (bytes + 255) & ~(size_t)255;
        return p;
    };

    unsigned short* h_buf   = (unsigned short*)alloc((size_t)N * XAGG_LD * 2); // xagg [N][960]; then h2 [N][784]
    unsigned short* gat_out = (unsigned short*)alloc((size_t)N * CP1A * 2);    // [N][832]; reused as gcn_out [N][784]
    unsigned short* xb      = (unsigned short*)alloc((size_t)N * KP_GAT * 2);
    unsigned short* Wgat_t  = (unsigned short*)alloc((size_t)CP1 * KP_GAT * 2);
    unsigned short* Wgcn_t  = (unsigned short*)alloc((size_t)CP2 * CP1A * 2);
    unsigned short* Wfcg1_t  = (unsigned short*)alloc((size_t)1500 * 1568 * 2);
    unsigned short* Wfc1_t   = (unsigned short*)alloc((size_t)1024 * 384 * 2);
    unsigned short* Wfc2_t   = (unsigned short*)alloc((size_t)512 * 1024 * 2);
    unsigned short* Wcat     = (unsigned short*)alloc((size_t)384 * KCAT * 2);  // block-diag, transposes write in place
    unsigned short* Acat     = (unsigned short*)alloc((size_t)G * KCAT * 2);    // [128][5920]
    unsigned short* gfeat_b  = (unsigned short*)alloc((size_t)G * 1568 * 2);
    unsigned short* xc_b     = (unsigned short*)alloc((size_t)G * 384 * 2);
    unsigned short* f1_b     = (unsigned short*)alloc((size_t)G * 1024 * 2);
    unsigned short* f2_b     = (unsigned short*)alloc((size_t)G * 512 * 2);
    float* skbuf  = (float*)alloc((size_t)7 * G * 1500 * 4);   // max split-K user: fcg1 KS=7
    float* bgat_p = (float*)alloc((size_t)CP1 * 4);
    float* bcat   = (float*)alloc((size_t)384 * 4);
    float* V_s    = (float*)alloc((size_t)F * H * 4);
    float* V_d    = (float*)alloc((size_t)F * H * 4);
    float* a_s    = (float*)alloc((size_t)N * H * 4);
    float* a_d    = (float*)alloc((size_t)N * H * 4);
    float* evb    = (float*)alloc((size_t)NE * H * 4);
    float* dinv   = (float*)alloc((size_t)N * 4);
    float* gfeat  = (float*)alloc((size_t)G * 1560 * 4);
    float* Mbuf   = (float*)alloc((size_t)G * BM_SPLIT * 26 * 256 * 4);
    float* Mfin   = (float*)alloc((size_t)G * 26 * 256 * 4);
    int* deg       = (int*)alloc((size_t)N * 4);
    int* row_start = (int*)alloc((size_t)(N + 1) * 4);
    int* fill_cnt  = (int*)alloc((size_t)N * 4);
    int* srcs      = (int*)alloc((size_t)NE * 4);
    int* bsum      = (int*)alloc((size_t)SCAN_NB * 4);
    int* bofs      = (int*)alloc((size_t)SCAN_NB * 4);
    int* gstart    = (int*)alloc((size_t)(G + 1) * 4);

    if (off > ws_size) {
        fprintf(stderr, "kernel_launch: workspace too small: need %zu have %zu\n", off, ws_size);
        return;
    }

    hipMemsetAsync(deg, 0, (size_t)N * 4, stream);
    hipMemsetAsync(fill_cnt, 0, (size_t)N * 4, stream);
    hipMemsetAsync(Acat, 0, (size_t)G * KCAT * 2, stream);     // gaps/K-pads must be 0 (NaN x 0 = NaN!)
    hipMemsetAsync(Wcat, 0, (size_t)384 * KCAT * 2, stream);   // off-diagonal blocks must be 0
    hipMemsetAsync(Wgcn_t, 0, (size_t)CP2 * CP1A * 2, stream); // pad k cols must be 0
    hipMemsetAsync(gfeat, 0, (size_t)G * 1560 * 4, stream);    // pool atomics accumulate

    dim3 tb(32, 8);

    // ---- weight builds + input cast ----
    k_cast_pad_x<<<CDIV(N * KP_GAT, 256), 256, 0, stream>>>(x, xb);
    k_build_Wgat_t<<<CDIV(KP_GAT * CP1, 256), 256, 0, stream>>>(W_gat, Wgat_t);
    k_build_biases<<<2, 256, 0, stream>>>(b_gat, bgat_p, b_fcg2, b_fc1xt, b_fc2xt, bcat);
    k_build_Wgcn_t<<<CDIV(C * CP2, 256), 256, 0, stream>>>(W_gcn, Wgcn_t);
    k_transpose_cast_t<<<dim3(CDIV(1568,32), CDIV(1500,32)), tb, 0, stream>>>(W_fcg1, Wfcg1_t, 1560, 1500, 1568, 1568);
    // fcg2 / fc2xt / fc1xt transposed DIRECTLY into Wcat segments (ld=KCAT):
    k_transpose_cast_t<<<dim3(CDIV(1504,32), CDIV(128,32)),  tb, 0, stream>>>(W_fcg2, Wcat, 1500, 128, 1504, KCAT);
    k_transpose_cast_t<<<dim3(CDIV(3872,32), CDIV(128,32)),  tb, 0, stream>>>(W_fc2xt, Wcat + (size_t)256 * KCAT + 1504, 3872, 128, 3872, KCAT);
    k_transpose_cast_t<<<dim3(CDIV(544,32),  CDIV(128,32)),  tb, 0, stream>>>(W_fc1xt, Wcat + (size_t)128 * KCAT + 5376, 544, 128, 544, KCAT);
    k_transpose_cast_t<<<dim3(CDIV(384,32),  CDIV(1024,32)), tb, 0, stream>>>(W_fc1, Wfc1_t, 384, 1024, 384, 384);
    k_transpose_cast_t<<<dim3(CDIV(1024,32), CDIV(512,32)),  tb, 0, stream>>>(W_fc2, Wfc2_t, 1024, 512, 1024, 1024);

    // ---- attention logits ----
    k_Vsd<<<CDIV(F * H, 256), 256, 0, stream>>>(W_gat, att_src, att_dst, V_s, V_d);
    k_ascores<<<CDIV(N, 256), 256, 0, stream>>>(x, V_s, V_d, a_s, a_d);

    // ---- CSR + graph ranges (3-phase parallel scan + fused dinv) ----
    count_deg<<<CDIV(NE, 256), 256, 0, stream>>>(ei, deg);
    k_scan_pass1<<<SCAN_NB, SCAN_B, 0, stream>>>(deg, bsum);
    k_scan_mid<<<1, SCAN_B, 0, stream>>>(bsum, bofs, row_start);
    k_scan_pass3<<<SCAN_NB, SCAN_B, 0, stream>>>(deg, bofs, row_start, dinv);
    fill_csr_ev<<<CDIV(NE, 256), 256, 0, stream>>>(ei, row_start, fill_cnt, srcs, a_s, a_d, evb);
    k_gstart<<<1, 256, 0, stream>>>(batch, gstart);   // batch sorted: binary search

    // ---- softmax (fused stats+alpha in place) ----
    k_softmax_alpha<<<CDIV(N * H, 256), 256, 0, stream>>>(row_start, evb);

    // ---- protein branches (independent; fill Acat segments early) ----
    k_build_M<<<dim3(G, BM_SPLIT), 256, 0, stream>>>(t2, Wc2, Mbuf);
    k_reduce_M<<<CDIV(G * 26 * 256, 256), 256, 0, stream>>>(Mbuf, Mfin);
    k_conv2<<<CDIV(G * 3872, 256), 256, 0, stream>>>(Mfin, emb, bc2, Acat + 1504, KCAT);
    k_conv1<<<CDIV(G * 544, 256), 256, 0, stream>>>(t1, Wc1, bc1, Acat + 5376, KCAT);

    // ---- GAT (linearity-swapped): aggregate x, then per-head GEMM ----
    gat_agg_x<<<N, 128, 0, stream>>>(xb, evb, srcs, row_start, h_buf);
    gemm_gat<<<dim3(CDIV(N, 256), H), 512, 0, stream>>>(h_buf, Wgat_t, bgat_p, gat_out);

    // ---- GCN: h2 = gat_out @ W_gcn  (256x128 tile, BK=64, K=832) ----
    {
        int rt = CDIV(N, 256), nct = CDIV(CP2, 128);
        gemm_mfma_256<<<rt * nct, 512, 0, stream>>>(gat_out, Wgcn_t, h_buf, nullptr, 0,
                                                    N, CP2, CP1A / 64, CP1A, CP1A, CP2, nct);
    }
    unsigned short* gcn_out = gat_out;
    gcn_agg<<<N, 128, 0, stream>>>(h_buf, dinv, srcs, row_start, b_gcn, gcn_out);
    k_pool<<<dim3(G, POOL_SPLIT), 128, 0, stream>>>(gcn_out, gstart, gfeat);
    k_pool_cast<<<CDIV(G * 1568, 256), 256, 0, stream>>>(gfeat, gstart, gfeat_b);

    // ---- graph FC: fcg1 -> Acat cols [0,1500); KS=7 (49 steps -> 7/split) ----
    gemm_mfma_sk<<<dim3(CDIV(1500,128), 7), 256, 0, stream>>>(gfeat_b, Wfcg1_t, skbuf,
                                                              G, 1500, 1568/32, 1568, 1568, CDIV(1500,128));
    k_sk_reduce<<<CDIV(G*1500, 256), 256, 0, stream>>>(skbuf, 7, G, 1500, b_fcg1, 1, Acat, KCAT);

    // ---- merged tail GEMM: xc = Acat @ Wcat^T; KS=24 (185 steps -> 8/split) ----
    gemm_mfma_sk<<<dim3(3, 24), 256, 0, stream>>>(Acat, Wcat, skbuf,
                                                  G, 384, KCAT/32, KCAT, KCAT, 3);
    k_sk_reduce<<<CDIV(G*384, 256), 256, 0, stream>>>(skbuf, 24, G, 384, bcat, 0, xc_b, 384);

    // ---- head: fc1 KS=6 (12 steps -> 2/split), fc2 KS=16 (32 -> 2/split) ----
    gemm_mfma_sk<<<dim3(CDIV(1024,128), 6), 256, 0, stream>>>(xc_b, Wfc1_t, skbuf,
                                                              G, 1024, 384/32, 384, 384, CDIV(1024,128));
    k_sk_reduce<<<CDIV(G*1024, 256), 256, 0, stream>>>(skbuf, 6, G, 1024, b_fc1, 1, f1_b, 1024);
    gemm_mfma_sk<<<dim3(CDIV(512,128), 16), 256, 0, stream>>>(f1_b, Wfc2_t, skbuf,
                                                              G, 512, 1024/32, 1024, 1024, CDIV(512,128));
    k_sk_reduce<<<CDIV(G*512, 256), 256, 0, stream>>>(skbuf, 16, G, 512, b_fc2, 1, f2_b, 512);
    k_fc_out<<<G, 64, 0, stream>>>(f2_b, W_out, b_out, (float*)d_out);
}